// Round 6
// baseline (427.252 us; speedup 1.0000x reference)
//
#include <hip/hip_runtime.h>
#include <math.h>

constexpr int N_NODES   = 100000;
constexpr int N_EDGES   = 1600000;
constexpr int MSG       = 16;
constexpr int HID       = 16;
constexpr int N_ETYPE   = 8;
constexpr int N_CLASSES = 40;

constexpr int CBSIZE   = 256;
constexpr int NBUCKET  = (N_NODES + CBSIZE - 1) / CBSIZE;    // 391
constexpr int NSUB     = 8;
constexpr int EPB      = 4096;
constexpr int NEBLK    = (N_EDGES + EPB - 1) / EPB;          // 391
constexpr int REC_CAP  = 5120;                               // fixed region per coarse bucket (16 sigma)
constexpr int NSLOT    = 2048;                               // (dst&255)*8 + etype
constexpr int A_STRIDE = 260;                                // per-ty bank offset 4

constexpr int NWUNIT   = N_NODES / 8;                        // 12500 wave-units (8 nodes each)
constexpr int FBLK     = 782;                                // <= 1024 resident at 4/CU; 782*4=3128 waves
constexpr int WSTRIDE  = FBLK * 4;                           // 3128: waves do 4 units (12 waves do 3)

__device__ __forceinline__ float sigmoidf_(float x) { return 1.0f / (1.0f + __expf(-x)); }
__device__ __forceinline__ float tanhf_(float x) { float e = __expf(2.0f * x); return 1.0f - 2.0f / (e + 1.0f); }

__device__ __forceinline__ unsigned f2bf(float f) {
    unsigned u = __float_as_uint(f);
    return (u + 0x7FFFu + ((u >> 16) & 1u)) >> 16;           // RNE
}
__device__ __forceinline__ float bflo(unsigned u) { return __uint_as_float(u << 16); }
__device__ __forceinline__ float bfhi(unsigned u) { return __uint_as_float(u & 0xFFFF0000u); }

// ---- Phase 0: pack features into bf16 table (3.2 MB, L2-resident) + init cursors ----
__global__ void __launch_bounds__(256) cvt_kernel(const float* __restrict__ features,
                                                  uint4* __restrict__ featb,
                                                  int* __restrict__ gcursor) {
    int i = blockIdx.x * 256 + threadIdx.x;                  // one uint4 = 8 bf16
    if (i < NBUCKET) gcursor[i] = i * REC_CAP;
    if (i * 8 >= N_NODES * HID) return;
    const float4* fp = reinterpret_cast<const float4*>(features + i * 8);
    float4 a = fp[0], b = fp[1];
    uint4 o;
    o.x = f2bf(a.x) | (f2bf(a.y) << 16);
    o.y = f2bf(a.z) | (f2bf(a.w) << 16);
    o.z = f2bf(b.x) | (f2bf(b.y) << 16);
    o.w = f2bf(b.z) | (f2bf(b.w) << 16);
    featb[i] = o;
}

// ---- Phase 1: coarse partition into fixed-capacity regions (round-0 exact) ----
// rec = (src << 11) | (etype << 8) | (dst & 255)
__global__ void __launch_bounds__(512) partition_kernel(
    const int* __restrict__ src,
    const int* __restrict__ dst,
    const int* __restrict__ etype,
    int* __restrict__ gcursor,
    int* __restrict__ records)
{
    __shared__ int srec[EPB];                 // 16 KB
    __shared__ unsigned short sbkt[EPB];      // 8 KB
    __shared__ int lh[NBUCKET];
    __shared__ int lscan[NBUCKET];
    __shared__ int lofs[NBUCKET];
    __shared__ int gbarr[NBUCKET];
    __shared__ int sscan[512];

    int t = threadIdx.x;
    int base = blockIdx.x * EPB;

    for (int i = t; i < NBUCKET; i += 512) lh[i] = 0;
    __syncthreads();

    int rr[8]; int bb[8];
    #pragma unroll
    for (int q = 0; q < 8; ++q) {
        int e = base + t + 512 * q;
        if (e < N_EDGES) {
            int d = dst[e];
            bb[q] = d >> 8;
            rr[q] = (src[e] << 11) | (etype[e] << 8) | (d & 255);
            atomicAdd(&lh[bb[q]], 1);
        } else bb[q] = -1;
    }
    __syncthreads();

    int i0 = t * 4;
    int v0 = 0, v1 = 0, v2 = 0, v3 = 0;
    if (i0     < NBUCKET) v0 = lh[i0];
    if (i0 + 1 < NBUCKET) v1 = lh[i0 + 1];
    if (i0 + 2 < NBUCKET) v2 = lh[i0 + 2];
    if (i0 + 3 < NBUCKET) v3 = lh[i0 + 3];
    int tsum = v0 + v1 + v2 + v3;
    sscan[t] = tsum;
    __syncthreads();
    for (int off = 1; off < 512; off <<= 1) {
        int tmp = (t >= off) ? sscan[t - off] : 0;
        __syncthreads();
        sscan[t] += tmp;
        __syncthreads();
    }
    int excl = sscan[t] - tsum;
    if (i0     < NBUCKET) { lscan[i0]     = excl; lofs[i0]     = excl; gbarr[i0]     = v0 ? atomicAdd(&gcursor[i0],     v0) : 0; } excl += v0;
    if (i0 + 1 < NBUCKET) { lscan[i0 + 1] = excl; lofs[i0 + 1] = excl; gbarr[i0 + 1] = v1 ? atomicAdd(&gcursor[i0 + 1], v1) : 0; } excl += v1;
    if (i0 + 2 < NBUCKET) { lscan[i0 + 2] = excl; lofs[i0 + 2] = excl; gbarr[i0 + 2] = v2 ? atomicAdd(&gcursor[i0 + 2], v2) : 0; } excl += v2;
    if (i0 + 3 < NBUCKET) { lscan[i0 + 3] = excl; lofs[i0 + 3] = excl; gbarr[i0 + 3] = v3 ? atomicAdd(&gcursor[i0 + 3], v3) : 0; }
    __syncthreads();

    #pragma unroll
    for (int q = 0; q < 8; ++q) {
        if (bb[q] >= 0) {
            int sidx = atomicAdd(&lofs[bb[q]], 1);
            srec[sidx] = rr[q];
            sbkt[sidx] = (unsigned short)bb[q];
        }
    }
    __syncthreads();

    int cnt = min(EPB, N_EDGES - base);
    for (int s2 = t; s2 < cnt; s2 += 512) {
        int b2 = sbkt[s2];
        int pos = gbarr[b2] + (s2 - lscan[b2]);
        if (pos < (b2 + 1) * REC_CAP)      // overflow clamp (never expected, 16 sigma)
            records[pos] = srec[s2];
    }
}

// ---- Phase 2: full 2048-bin counting sort per coarse bucket (round-0 exact) ----
// key = (dst&255)*8 + etype; emits slot_off[cb][2049] and sorted records2.
__global__ void __launch_bounds__(256) partition2_kernel(
    const int* __restrict__ gcursor,
    const int* __restrict__ records,
    int* __restrict__ records2,
    int* __restrict__ slot_off)
{
    __shared__ int hist[NSLOT];    // 8 KB; becomes cursor after scan
    __shared__ int sscan[256];
    __shared__ int srec[REC_CAP];  // 20 KB

    int cb = blockIdx.x;
    int beg = cb * REC_CAP;
    int cnt = min(gcursor[cb] - beg, REC_CAP);
    int t = threadIdx.x;

    #pragma unroll
    for (int j = 0; j < 8; ++j) hist[t * 8 + j] = 0;
    __syncthreads();

    for (int i = t; i < cnt; i += 256) {
        int r = records[beg + i];
        atomicAdd(&hist[((r & 255) << 3) | ((r >> 8) & 7)], 1);
    }
    __syncthreads();

    int loc[8]; int tsum = 0;
    #pragma unroll
    for (int j = 0; j < 8; ++j) { loc[j] = hist[t * 8 + j]; tsum += loc[j]; }
    sscan[t] = tsum;
    __syncthreads();
    for (int off = 1; off < 256; off <<= 1) {
        int tmp = (t >= off) ? sscan[t - off] : 0;
        __syncthreads();
        sscan[t] += tmp;
        __syncthreads();
    }
    int excl = sscan[t] - tsum;
    #pragma unroll
    for (int j = 0; j < 8; ++j) {
        slot_off[cb * (NSLOT + 1) + t * 8 + j] = beg + excl;
        hist[t * 8 + j] = excl;    // cursor
        excl += loc[j];
    }
    if (t == 0) slot_off[cb * (NSLOT + 1) + NSLOT] = beg + cnt;
    __syncthreads();

    for (int i = t; i < cnt; i += 256) {
        int r = records[beg + i];
        int pos = atomicAdd(&hist[((r & 255) << 3) | ((r >> 8) & 7)], 1);
        srec[pos] = r;
    }
    __syncthreads();
    for (int i = t; i < cnt; i += 256) records2[beg + i] = srec[i];
}

// ---- Phase 3: wave-autonomous fused. Unit = 1 wave = 8 nodes = 64 slots. ----
// Lane = dl*8 + q: dl = node-in-unit (0..7), q = etype (0..7).
// All dataflow (edge acc, etype reduce, GRU, transpose, head) stays inside the
// wave's 8-lane node groups -> ZERO barriers in the main loop. Output written
// directly: wave covers 8*160B = 1280B contiguous (20 full 64B lines, no RMW).
// 12500 units over 3128 waves (782 blocks, all resident at 4/CU): 4 units/wave,
// uniform; waves drift independently so Poisson run-length variance averages
// instead of gating 16 waves per block barrier.
__global__ void __launch_bounds__(256, 4) fused_kernel(
    const uint4* __restrict__ featb,
    const float* __restrict__ features,
    const int*   __restrict__ slot_off,
    const int*   __restrict__ records2,
    const float* __restrict__ edge_matrix,
    const float* __restrict__ w_ih,
    const float* __restrict__ w_hh,
    const float* __restrict__ b_ih,
    const float* __restrict__ b_hh,
    const float* __restrict__ out_w,
    const float* __restrict__ out_b,
    float*       __restrict__ out)
{
    __shared__ float A[N_ETYPE * A_STRIDE];   // 8.3 KB
    __shared__ float wihL[3 * HID * 17];      // 3.2 KB (row stride 17)
    __shared__ float whhL[3 * HID * 17];      // 3.2 KB
    __shared__ float outwL[N_CLASSES * 17];   // 2.7 KB
    __shared__ float bihL[3 * HID];
    __shared__ float bhhL[3 * HID];
    __shared__ float outbL[N_CLASSES];

    int t = threadIdx.x;
    int lane = t & 63, wid = t >> 6;
    int dl = lane >> 3, q = lane & 7;
    const float4* feat4 = reinterpret_cast<const float4*>(features);

    // stage constants ONCE (padded layouts)
    for (int i = t; i < N_ETYPE * MSG * HID; i += 256)
        A[(i >> 8) * A_STRIDE + (i & 255)] = edge_matrix[i];
    for (int i = t; i < 3 * HID * MSG; i += 256) wihL[(i >> 4) * 17 + (i & 15)] = w_ih[i];
    for (int i = t; i < 3 * HID * HID; i += 256) whhL[(i >> 4) * 17 + (i & 15)] = w_hh[i];
    for (int i = t; i < N_CLASSES * HID; i += 256) outwL[(i >> 4) * 17 + (i & 15)] = out_w[i];
    if (t < 48) bihL[t] = b_ih[t];
    else if (t < 96) bhhL[t - 48] = b_hh[t - 48];
    else if (t < 136) outbL[t - 96] = out_b[t - 96];
    __syncthreads();   // the ONLY barrier

    int gw = blockIdx.x * 4 + wid;   // global wave id, 0..3127

    for (int m = gw; m < NWUNIT; m += WSTRIDE) {
        // unit m: nodes m*8 .. m*8+7; coarse bucket cb = m>>5; slots (m&31)*64 ..
        int cb = m >> 5;
        int so = cb * (NSLOT + 1) + (m & 31) * 64;
        int begin = slot_off[so + lane];
        int end   = slot_off[so + lane + 1];

        // ---- edge phase: serial register accumulation over this lane's slot run ----
        float acc[16];
        #pragma unroll
        for (int k = 0; k < 16; ++k) acc[k] = 0.0f;
        for (int i = begin; i < end; ++i) {
            int rec = records2[i];
            int sn = rec >> 11;
            uint4 ua = featb[2 * sn], ub = featb[2 * sn + 1];
            acc[0]  += bflo(ua.x); acc[1]  += bfhi(ua.x);
            acc[2]  += bflo(ua.y); acc[3]  += bfhi(ua.y);
            acc[4]  += bflo(ua.z); acc[5]  += bfhi(ua.z);
            acc[6]  += bflo(ua.w); acc[7]  += bfhi(ua.w);
            acc[8]  += bflo(ub.x); acc[9]  += bfhi(ub.x);
            acc[10] += bflo(ub.y); acc[11] += bfhi(ub.y);
            acc[12] += bflo(ub.z); acc[13] += bfhi(ub.z);
            acc[14] += bflo(ub.w); acc[15] += bfhi(ub.w);
        }

        // ---- matvec partial: p[mm] = A[q][mm][:] . acc  (broadcast LDS reads) ----
        float p[16];
        {
            const float* Aq = &A[q * A_STRIDE];
            #pragma unroll
            for (int mm = 0; mm < 16; ++mm) {
                const float4* Ar = reinterpret_cast<const float4*>(Aq + mm * 16);
                float4 x0 = Ar[0], x1 = Ar[1], x2 = Ar[2], x3 = Ar[3];
                p[mm] = x0.x*acc[0]  + x0.y*acc[1]  + x0.z*acc[2]  + x0.w*acc[3]
                      + x1.x*acc[4]  + x1.y*acc[5]  + x1.z*acc[6]  + x1.w*acc[7]
                      + x2.x*acc[8]  + x2.y*acc[9]  + x2.z*acc[10] + x2.w*acc[11]
                      + x3.x*acc[12] + x3.y*acc[13] + x3.z*acc[14] + x3.w*acc[15];
            }
        }
        // ---- reduce the 8 etype partials per node (within the 8-lane group) ----
        #pragma unroll
        for (int mm = 0; mm < 16; ++mm) {
            p[mm] += __shfl_xor(p[mm], 1, 64);
            p[mm] += __shfl_xor(p[mm], 2, 64);
            p[mm] += __shfl_xor(p[mm], 4, 64);
        }

        // ---- GRU: lane (dl,q) computes gate rows j = 2q, 2q+1 for node n ----
        int n = m * 8 + dl;
        float hva[16];
        {
            const float4* hp = feat4 + (size_t)n * 4;
            float4 h0 = hp[0], h1 = hp[1], h2 = hp[2], h3 = hp[3];
            hva[0]=h0.x; hva[1]=h0.y; hva[2]=h0.z; hva[3]=h0.w;
            hva[4]=h1.x; hva[5]=h1.y; hva[6]=h1.z; hva[7]=h1.w;
            hva[8]=h2.x; hva[9]=h2.y; hva[10]=h2.z; hva[11]=h2.w;
            hva[12]=h3.x; hva[13]=h3.y; hva[14]=h3.z; hva[15]=h3.w;
        }
        float hg[2];
        #pragma unroll
        for (int jj = 0; jj < 2; ++jj) {
            int j = 2 * q + jj;
            float ir  = bihL[j];
            float iz  = bihL[j + HID];
            float inn = bihL[j + 2 * HID];
            float hr  = bhhL[j];
            float hz  = bhhL[j + HID];
            float hnn = bhhL[j + 2 * HID];
            const float* wir = &wihL[j * 17];
            const float* wiz = &wihL[(j + HID) * 17];
            const float* win = &wihL[(j + 2 * HID) * 17];
            const float* whr = &whhL[j * 17];
            const float* whz = &whhL[(j + HID) * 17];
            const float* whn = &whhL[(j + 2 * HID) * 17];
            #pragma unroll
            for (int k = 0; k < HID; ++k) {
                ir  += wir[k] * p[k];
                iz  += wiz[k] * p[k];
                inn += win[k] * p[k];
                hr  += whr[k] * hva[k];
                hz  += whz[k] * hva[k];
                hnn += whn[k] * hva[k];
            }
            float rg = sigmoidf_(ir + hr);
            float zg = sigmoidf_(iz + hz);
            float cg = tanhf_(inn + rg * hnn);
            float hj = features[(size_t)n * HID + j];   // L1-hot scalar (avoids runtime reg-index)
            hg[jj] = (1.0f - zg) * cg + zg * hj;
        }

        // ---- in-wave transpose: gather node dl's full h from its 8-lane group ----
        int lanebase = lane & 56;
        float hh[16];
        #pragma unroll
        for (int qq = 0; qq < 8; ++qq) {
            hh[2 * qq]     = __shfl(hg[0], lanebase + qq, 64);
            hh[2 * qq + 1] = __shfl(hg[1], lanebase + qq, 64);
        }

        // ---- head: lane (dl,q) computes classes 5q..5q+4, direct stores ----
        // wave writes 8 nodes x 160B = 1280B contiguous -> 20 full 64B lines
        float* op = out + (size_t)n * N_CLASSES + 5 * q;
        #pragma unroll
        for (int cc = 0; cc < 5; ++cc) {
            int c = 5 * q + cc;
            float a2 = outbL[c];
            const float* wr = &outwL[c * 17];
            #pragma unroll
            for (int k = 0; k < HID; ++k) a2 += wr[k] * hh[k];
            op[cc] = a2;
        }
    }
}

extern "C" void kernel_launch(void* const* d_in, const int* in_sizes, int n_in,
                              void* d_out, int out_size, void* d_ws, size_t ws_size,
                              hipStream_t stream) {
    const float* features    = (const float*)d_in[0];
    const int*   src         = (const int*)  d_in[1];
    const int*   dst         = (const int*)  d_in[2];
    const int*   etype       = (const int*)  d_in[3];
    const float* edge_matrix = (const float*)d_in[4];
    const float* w_ih        = (const float*)d_in[5];
    const float* w_hh        = (const float*)d_in[6];
    const float* b_ih        = (const float*)d_in[7];
    const float* b_hh        = (const float*)d_in[8];
    const float* out_w       = (const float*)d_in[9];
    const float* out_b       = (const float*)d_in[10];
    float* out = (float*)d_out;

    // ws (ints): gcursor[NB] | slot_off[NB*2049] | records[NB*CAP] | records2[NB*CAP] | featb (16B aligned)
    int* gcursor  = (int*)d_ws;
    int* slot_off = gcursor + NBUCKET;
    int* records  = slot_off + NBUCKET * (NSLOT + 1);
    int* records2 = records + NBUCKET * REC_CAP;
    size_t featb_off = ((size_t)((char*)(records2 + NBUCKET * REC_CAP) - (char*)d_ws) + 15) & ~15ull;
    uint4* featb = (uint4*)((char*)d_ws + featb_off);

    cvt_kernel<<<(N_NODES * HID / 8 + 255) / 256, 256, 0, stream>>>(features, featb, gcursor);
    partition_kernel<<<NEBLK, 512, 0, stream>>>(src, dst, etype, gcursor, records);
    partition2_kernel<<<NBUCKET, 256, 0, stream>>>(gcursor, records, records2, slot_off);
    fused_kernel<<<FBLK, 256, 0, stream>>>(
        featb, features, slot_off, records2, edge_matrix,
        w_ih, w_hh, b_ih, b_hh, out_w, out_b, out);
}

// Round 7
// 419.439 us; speedup vs baseline: 1.0186x; 1.0186x over previous
//
#include <hip/hip_runtime.h>
#include <math.h>

constexpr int N_NODES   = 100000;
constexpr int N_EDGES   = 1600000;
constexpr int MSG       = 16;
constexpr int HID       = 16;
constexpr int N_ETYPE   = 8;
constexpr int N_CLASSES = 40;

constexpr int CBSIZE   = 256;
constexpr int NBUCKET  = (N_NODES + CBSIZE - 1) / CBSIZE;    // 391
constexpr int NSUB     = 8;
constexpr int EPB      = 4096;
constexpr int NEBLK    = (N_EDGES + EPB - 1) / EPB;          // 391
constexpr int REC_CAP  = 5120;                               // fixed region per coarse bucket (16 sigma)
constexpr int NSLOT    = 2048;                               // (dst&255)*8 + etype
constexpr int A_STRIDE = 260;                                // per-ty bank offset 4

constexpr int NWUNIT   = N_NODES / 8;                        // 12500 wave-units (8 nodes each)
constexpr int FBLK     = 782;                                // <= 1024 resident at 4/CU; 782*4=3128 waves
constexpr int WSTRIDE  = FBLK * 4;                           // 3128: waves do 4 units (12 waves do 3)

__device__ __forceinline__ float sigmoidf_(float x) { return 1.0f / (1.0f + __expf(-x)); }
__device__ __forceinline__ float tanhf_(float x) { float e = __expf(2.0f * x); return 1.0f - 2.0f / (e + 1.0f); }

__device__ __forceinline__ unsigned f2bf(float f) {
    unsigned u = __float_as_uint(f);
    return (u + 0x7FFFu + ((u >> 16) & 1u)) >> 16;           // RNE
}
__device__ __forceinline__ float bflo(unsigned u) { return __uint_as_float(u << 16); }
__device__ __forceinline__ float bfhi(unsigned u) { return __uint_as_float(u & 0xFFFF0000u); }

// ---- Phase 0: pack features into bf16 table (3.2 MB, L2-resident) + init cursors ----
__global__ void __launch_bounds__(256) cvt_kernel(const float* __restrict__ features,
                                                  uint4* __restrict__ featb,
                                                  int* __restrict__ gcursor) {
    int i = blockIdx.x * 256 + threadIdx.x;                  // one uint4 = 8 bf16
    if (i < NBUCKET) gcursor[i] = i * REC_CAP;
    if (i * 8 >= N_NODES * HID) return;
    const float4* fp = reinterpret_cast<const float4*>(features + i * 8);
    float4 a = fp[0], b = fp[1];
    uint4 o;
    o.x = f2bf(a.x) | (f2bf(a.y) << 16);
    o.y = f2bf(a.z) | (f2bf(a.w) << 16);
    o.z = f2bf(b.x) | (f2bf(b.y) << 16);
    o.w = f2bf(b.z) | (f2bf(b.w) << 16);
    featb[i] = o;
}

// ---- Phase 1: coarse partition into fixed-capacity regions (round-0 exact) ----
// rec = (src << 11) | (etype << 8) | (dst & 255)
__global__ void __launch_bounds__(512) partition_kernel(
    const int* __restrict__ src,
    const int* __restrict__ dst,
    const int* __restrict__ etype,
    int* __restrict__ gcursor,
    int* __restrict__ records)
{
    __shared__ int srec[EPB];                 // 16 KB
    __shared__ unsigned short sbkt[EPB];      // 8 KB
    __shared__ int lh[NBUCKET];
    __shared__ int lscan[NBUCKET];
    __shared__ int lofs[NBUCKET];
    __shared__ int gbarr[NBUCKET];
    __shared__ int sscan[512];

    int t = threadIdx.x;
    int base = blockIdx.x * EPB;

    for (int i = t; i < NBUCKET; i += 512) lh[i] = 0;
    __syncthreads();

    int rr[8]; int bb[8];
    #pragma unroll
    for (int q = 0; q < 8; ++q) {
        int e = base + t + 512 * q;
        if (e < N_EDGES) {
            int d = dst[e];
            bb[q] = d >> 8;
            rr[q] = (src[e] << 11) | (etype[e] << 8) | (d & 255);
            atomicAdd(&lh[bb[q]], 1);
        } else bb[q] = -1;
    }
    __syncthreads();

    int i0 = t * 4;
    int v0 = 0, v1 = 0, v2 = 0, v3 = 0;
    if (i0     < NBUCKET) v0 = lh[i0];
    if (i0 + 1 < NBUCKET) v1 = lh[i0 + 1];
    if (i0 + 2 < NBUCKET) v2 = lh[i0 + 2];
    if (i0 + 3 < NBUCKET) v3 = lh[i0 + 3];
    int tsum = v0 + v1 + v2 + v3;
    sscan[t] = tsum;
    __syncthreads();
    for (int off = 1; off < 512; off <<= 1) {
        int tmp = (t >= off) ? sscan[t - off] : 0;
        __syncthreads();
        sscan[t] += tmp;
        __syncthreads();
    }
    int excl = sscan[t] - tsum;
    if (i0     < NBUCKET) { lscan[i0]     = excl; lofs[i0]     = excl; gbarr[i0]     = v0 ? atomicAdd(&gcursor[i0],     v0) : 0; } excl += v0;
    if (i0 + 1 < NBUCKET) { lscan[i0 + 1] = excl; lofs[i0 + 1] = excl; gbarr[i0 + 1] = v1 ? atomicAdd(&gcursor[i0 + 1], v1) : 0; } excl += v1;
    if (i0 + 2 < NBUCKET) { lscan[i0 + 2] = excl; lofs[i0 + 2] = excl; gbarr[i0 + 2] = v2 ? atomicAdd(&gcursor[i0 + 2], v2) : 0; } excl += v2;
    if (i0 + 3 < NBUCKET) { lscan[i0 + 3] = excl; lofs[i0 + 3] = excl; gbarr[i0 + 3] = v3 ? atomicAdd(&gcursor[i0 + 3], v3) : 0; }
    __syncthreads();

    #pragma unroll
    for (int q = 0; q < 8; ++q) {
        if (bb[q] >= 0) {
            int sidx = atomicAdd(&lofs[bb[q]], 1);
            srec[sidx] = rr[q];
            sbkt[sidx] = (unsigned short)bb[q];
        }
    }
    __syncthreads();

    int cnt = min(EPB, N_EDGES - base);
    for (int s2 = t; s2 < cnt; s2 += 512) {
        int b2 = sbkt[s2];
        int pos = gbarr[b2] + (s2 - lscan[b2]);
        if (pos < (b2 + 1) * REC_CAP)      // overflow clamp (never expected, 16 sigma)
            records[pos] = srec[s2];
    }
}

// ---- Phase 2: full 2048-bin counting sort per coarse bucket (round-0 exact) ----
// key = (dst&255)*8 + etype; emits slot_off[cb][2049] and sorted records2.
__global__ void __launch_bounds__(256) partition2_kernel(
    const int* __restrict__ gcursor,
    const int* __restrict__ records,
    int* __restrict__ records2,
    int* __restrict__ slot_off)
{
    __shared__ int hist[NSLOT];    // 8 KB; becomes cursor after scan
    __shared__ int sscan[256];
    __shared__ int srec[REC_CAP];  // 20 KB

    int cb = blockIdx.x;
    int beg = cb * REC_CAP;
    int cnt = min(gcursor[cb] - beg, REC_CAP);
    int t = threadIdx.x;

    #pragma unroll
    for (int j = 0; j < 8; ++j) hist[t * 8 + j] = 0;
    __syncthreads();

    for (int i = t; i < cnt; i += 256) {
        int r = records[beg + i];
        atomicAdd(&hist[((r & 255) << 3) | ((r >> 8) & 7)], 1);
    }
    __syncthreads();

    int loc[8]; int tsum = 0;
    #pragma unroll
    for (int j = 0; j < 8; ++j) { loc[j] = hist[t * 8 + j]; tsum += loc[j]; }
    sscan[t] = tsum;
    __syncthreads();
    for (int off = 1; off < 256; off <<= 1) {
        int tmp = (t >= off) ? sscan[t - off] : 0;
        __syncthreads();
        sscan[t] += tmp;
        __syncthreads();
    }
    int excl = sscan[t] - tsum;
    #pragma unroll
    for (int j = 0; j < 8; ++j) {
        slot_off[cb * (NSLOT + 1) + t * 8 + j] = beg + excl;
        hist[t * 8 + j] = excl;    // cursor
        excl += loc[j];
    }
    if (t == 0) slot_off[cb * (NSLOT + 1) + NSLOT] = beg + cnt;
    __syncthreads();

    for (int i = t; i < cnt; i += 256) {
        int r = records[beg + i];
        int pos = atomicAdd(&hist[((r & 255) << 3) | ((r >> 8) & 7)], 1);
        srec[pos] = r;
    }
    __syncthreads();
    for (int i = t; i < cnt; i += 256) records2[beg + i] = srec[i];
}

// ---- Phase 3: wave-autonomous fused. Unit = 1 wave = 8 nodes = 64 slots. ----
// Lane = dl*8 + q: dl = node-in-unit (0..7), q = etype (0..7).
// ZERO block barriers in the main loop. Output: head results staged through a
// WAVE-PRIVATE LDS tile (intra-wave ds ordering needs no barrier), then one
// coalesced float4 copy -> full 64B lines only (round 6's scattered scalar
// stores caused 287MB RMW writes + L2 pollution that evicted featb -> 636MB fetch).
__global__ void __launch_bounds__(256, 4) fused_kernel(
    const uint4* __restrict__ featb,
    const float* __restrict__ features,
    const int*   __restrict__ slot_off,
    const int*   __restrict__ records2,
    const float* __restrict__ edge_matrix,
    const float* __restrict__ w_ih,
    const float* __restrict__ w_hh,
    const float* __restrict__ b_ih,
    const float* __restrict__ b_hh,
    const float* __restrict__ out_w,
    const float* __restrict__ out_b,
    float*       __restrict__ out)
{
    __shared__ float A[N_ETYPE * A_STRIDE];   // 8.3 KB
    __shared__ float wihL[3 * HID * 17];      // 3.2 KB (row stride 17)
    __shared__ float whhL[3 * HID * 17];      // 3.2 KB
    __shared__ float outwL[N_CLASSES * 17];   // 2.7 KB
    __shared__ float bihL[3 * HID];
    __shared__ float bhhL[3 * HID];
    __shared__ float outbL[N_CLASSES];
    __shared__ float outS[4][8 * 44];         // 5.6 KB, wave-private tiles

    int t = threadIdx.x;
    int lane = t & 63, wid = t >> 6;
    int dl = lane >> 3, q = lane & 7;
    const float4* feat4 = reinterpret_cast<const float4*>(features);

    // stage constants ONCE (padded layouts)
    for (int i = t; i < N_ETYPE * MSG * HID; i += 256)
        A[(i >> 8) * A_STRIDE + (i & 255)] = edge_matrix[i];
    for (int i = t; i < 3 * HID * MSG; i += 256) wihL[(i >> 4) * 17 + (i & 15)] = w_ih[i];
    for (int i = t; i < 3 * HID * HID; i += 256) whhL[(i >> 4) * 17 + (i & 15)] = w_hh[i];
    for (int i = t; i < N_CLASSES * HID; i += 256) outwL[(i >> 4) * 17 + (i & 15)] = out_w[i];
    if (t < 48) bihL[t] = b_ih[t];
    else if (t < 96) bhhL[t - 48] = b_hh[t - 48];
    else if (t < 136) outbL[t - 96] = out_b[t - 96];
    __syncthreads();   // the ONLY barrier

    float* myS = outS[wid];
    int gw = blockIdx.x * 4 + wid;   // global wave id, 0..3127

    for (int m = gw; m < NWUNIT; m += WSTRIDE) {
        // unit m: nodes m*8 .. m*8+7; coarse bucket cb = m>>5; slots (m&31)*64 ..
        int cb = m >> 5;
        int so = cb * (NSLOT + 1) + (m & 31) * 64;
        int begin = slot_off[so + lane];
        int end   = slot_off[so + lane + 1];

        // ---- edge phase: serial register accumulation over this lane's slot run ----
        float acc[16];
        #pragma unroll
        for (int k = 0; k < 16; ++k) acc[k] = 0.0f;
        for (int i = begin; i < end; ++i) {
            int rec = records2[i];
            int sn = rec >> 11;
            uint4 ua = featb[2 * sn], ub = featb[2 * sn + 1];
            acc[0]  += bflo(ua.x); acc[1]  += bfhi(ua.x);
            acc[2]  += bflo(ua.y); acc[3]  += bfhi(ua.y);
            acc[4]  += bflo(ua.z); acc[5]  += bfhi(ua.z);
            acc[6]  += bflo(ua.w); acc[7]  += bfhi(ua.w);
            acc[8]  += bflo(ub.x); acc[9]  += bfhi(ub.x);
            acc[10] += bflo(ub.y); acc[11] += bfhi(ub.y);
            acc[12] += bflo(ub.z); acc[13] += bfhi(ub.z);
            acc[14] += bflo(ub.w); acc[15] += bfhi(ub.w);
        }

        // ---- matvec partial: p[mm] = A[q][mm][:] . acc  (broadcast LDS reads) ----
        float p[16];
        {
            const float* Aq = &A[q * A_STRIDE];
            #pragma unroll
            for (int mm = 0; mm < 16; ++mm) {
                const float4* Ar = reinterpret_cast<const float4*>(Aq + mm * 16);
                float4 x0 = Ar[0], x1 = Ar[1], x2 = Ar[2], x3 = Ar[3];
                p[mm] = x0.x*acc[0]  + x0.y*acc[1]  + x0.z*acc[2]  + x0.w*acc[3]
                      + x1.x*acc[4]  + x1.y*acc[5]  + x1.z*acc[6]  + x1.w*acc[7]
                      + x2.x*acc[8]  + x2.y*acc[9]  + x2.z*acc[10] + x2.w*acc[11]
                      + x3.x*acc[12] + x3.y*acc[13] + x3.z*acc[14] + x3.w*acc[15];
            }
        }
        // ---- reduce the 8 etype partials per node (within the 8-lane group) ----
        #pragma unroll
        for (int mm = 0; mm < 16; ++mm) {
            p[mm] += __shfl_xor(p[mm], 1, 64);
            p[mm] += __shfl_xor(p[mm], 2, 64);
            p[mm] += __shfl_xor(p[mm], 4, 64);
        }

        // ---- GRU: lane (dl,q) computes gate rows j = 2q, 2q+1 for node n ----
        int n = m * 8 + dl;
        float hva[16];
        {
            const float4* hp = feat4 + (size_t)n * 4;
            float4 h0 = hp[0], h1 = hp[1], h2 = hp[2], h3 = hp[3];
            hva[0]=h0.x; hva[1]=h0.y; hva[2]=h0.z; hva[3]=h0.w;
            hva[4]=h1.x; hva[5]=h1.y; hva[6]=h1.z; hva[7]=h1.w;
            hva[8]=h2.x; hva[9]=h2.y; hva[10]=h2.z; hva[11]=h2.w;
            hva[12]=h3.x; hva[13]=h3.y; hva[14]=h3.z; hva[15]=h3.w;
        }
        float hg[2];
        #pragma unroll
        for (int jj = 0; jj < 2; ++jj) {
            int j = 2 * q + jj;
            float ir  = bihL[j];
            float iz  = bihL[j + HID];
            float inn = bihL[j + 2 * HID];
            float hr  = bhhL[j];
            float hz  = bhhL[j + HID];
            float hnn = bhhL[j + 2 * HID];
            const float* wir = &wihL[j * 17];
            const float* wiz = &wihL[(j + HID) * 17];
            const float* win = &wihL[(j + 2 * HID) * 17];
            const float* whr = &whhL[j * 17];
            const float* whz = &whhL[(j + HID) * 17];
            const float* whn = &whhL[(j + 2 * HID) * 17];
            #pragma unroll
            for (int k = 0; k < HID; ++k) {
                ir  += wir[k] * p[k];
                iz  += wiz[k] * p[k];
                inn += win[k] * p[k];
                hr  += whr[k] * hva[k];
                hz  += whz[k] * hva[k];
                hnn += whn[k] * hva[k];
            }
            float rg = sigmoidf_(ir + hr);
            float zg = sigmoidf_(iz + hz);
            float cg = tanhf_(inn + rg * hnn);
            float hj = features[(size_t)n * HID + j];   // same line as feat4 read -> L1 hit
            hg[jj] = (1.0f - zg) * cg + zg * hj;
        }

        // ---- in-wave transpose: gather node dl's full h from its 8-lane group ----
        int lanebase = lane & 56;
        float hh[16];
        #pragma unroll
        for (int qq = 0; qq < 8; ++qq) {
            hh[2 * qq]     = __shfl(hg[0], lanebase + qq, 64);
            hh[2 * qq + 1] = __shfl(hg[1], lanebase + qq, 64);
        }

        // ---- head: lane (dl,q) computes classes 5q..5q+4 into wave-private outS ----
        #pragma unroll
        for (int cc = 0; cc < 5; ++cc) {
            int c = 5 * q + cc;
            float a2 = outbL[c];
            const float* wr = &outwL[c * 17];
            #pragma unroll
            for (int k = 0; k < HID; ++k) a2 += wr[k] * hh[k];
            myS[dl * 44 + c] = a2;
        }
        // intra-wave LDS write->read: ordered by lgkmcnt, no barrier needed

        // ---- coalesced float4 output copy: 8 nodes x 160B = 80 float4, full lines ----
        {
            float4* ob4 = reinterpret_cast<float4*>(out + (size_t)(m * 8) * N_CLASSES);
            #pragma unroll
            for (int rep = 0; rep < 2; ++rep) {
                int i = lane + rep * 64;
                if (i < 80) {
                    int node = i / 10, qq = i - node * 10;
                    ob4[i] = *reinterpret_cast<const float4*>(&myS[node * 44 + qq * 4]);
                }
            }
        }
    }
}

extern "C" void kernel_launch(void* const* d_in, const int* in_sizes, int n_in,
                              void* d_out, int out_size, void* d_ws, size_t ws_size,
                              hipStream_t stream) {
    const float* features    = (const float*)d_in[0];
    const int*   src         = (const int*)  d_in[1];
    const int*   dst         = (const int*)  d_in[2];
    const int*   etype       = (const int*)  d_in[3];
    const float* edge_matrix = (const float*)d_in[4];
    const float* w_ih        = (const float*)d_in[5];
    const float* w_hh        = (const float*)d_in[6];
    const float* b_ih        = (const float*)d_in[7];
    const float* b_hh        = (const float*)d_in[8];
    const float* out_w       = (const float*)d_in[9];
    const float* out_b       = (const float*)d_in[10];
    float* out = (float*)d_out;

    // ws (ints): gcursor[NB] | slot_off[NB*2049] | records[NB*CAP] | records2[NB*CAP] | featb (16B aligned)
    int* gcursor  = (int*)d_ws;
    int* slot_off = gcursor + NBUCKET;
    int* records  = slot_off + NBUCKET * (NSLOT + 1);
    int* records2 = records + NBUCKET * REC_CAP;
    size_t featb_off = ((size_t)((char*)(records2 + NBUCKET * REC_CAP) - (char*)d_ws) + 15) & ~15ull;
    uint4* featb = (uint4*)((char*)d_ws + featb_off);

    cvt_kernel<<<(N_NODES * HID / 8 + 255) / 256, 256, 0, stream>>>(features, featb, gcursor);
    partition_kernel<<<NEBLK, 512, 0, stream>>>(src, dst, etype, gcursor, records);
    partition2_kernel<<<NBUCKET, 256, 0, stream>>>(gcursor, records, records2, slot_off);
    fused_kernel<<<FBLK, 256, 0, stream>>>(
        featb, features, slot_off, records2, edge_matrix,
        w_ih, w_hh, b_ih, b_hh, out_w, out_b, out);
}

// Round 8
// 114.580 us; speedup vs baseline: 3.7288x; 3.6606x over previous
//
#include <hip/hip_runtime.h>
#include <math.h>

constexpr int N_NODES   = 100000;
constexpr int N_EDGES   = 1600000;
constexpr int MSG       = 16;
constexpr int HID       = 16;
constexpr int N_ETYPE   = 8;
constexpr int N_CLASSES = 40;

constexpr int CBSIZE   = 256;
constexpr int NBUCKET  = (N_NODES + CBSIZE - 1) / CBSIZE;    // 391
constexpr int SBSIZE   = 32;
constexpr int NSUB     = 8;
constexpr int NSB      = NBUCKET * NSUB;                     // 3128
constexpr int EPB      = 4096;
constexpr int NEBLK    = (N_EDGES + EPB - 1) / EPB;          // 391
constexpr int REC_CAP  = 5120;                               // fixed region per coarse bucket (16 sigma)
constexpr int FGRID    = 1536;                               // 6 blocks/CU x 256 CU, all resident at t=0
constexpr int NSLOT    = 2048;                               // (dst&255)*8 + etype
constexpr int A_STRIDE = 260;                                // per-ty bank offset 4
constexpr int NFEATB   = N_NODES * HID / 8;                  // 200000 uint4 featb entries

__device__ __forceinline__ float sigmoidf_(float x) { return 1.0f / (1.0f + __expf(-x)); }
__device__ __forceinline__ float tanhf_(float x) { float e = __expf(2.0f * x); return 1.0f - 2.0f / (e + 1.0f); }

__device__ __forceinline__ unsigned f2bf(float f) {
    unsigned u = __float_as_uint(f);
    return (u + 0x7FFFu + ((u >> 16) & 1u)) >> 16;           // RNE
}
__device__ __forceinline__ float bflo(unsigned u) { return __uint_as_float(u << 16); }
__device__ __forceinline__ float bfhi(unsigned u) { return __uint_as_float(u & 0xFFFF0000u); }

// ---- Phase 1: coarse partition + featb conversion (cvt merged as prologue) ----
// rec = (src << 11) | (etype << 8) | (dst & 255)
// gcursor is a zero-initialized COUNT array (memset by host); record position is
// cb*REC_CAP + relative rank -> identical semantics to round-0's cursor scheme.
__global__ void __launch_bounds__(512) partition_kernel(
    const float* __restrict__ features,
    uint4* __restrict__ featb,
    const int* __restrict__ src,
    const int* __restrict__ dst,
    const int* __restrict__ etype,
    int* __restrict__ gcursor,
    int* __restrict__ records)
{
    __shared__ int srec[EPB];                 // 16 KB
    __shared__ unsigned short sbkt[EPB];      // 8 KB
    __shared__ int lh[NBUCKET];
    __shared__ int lscan[NBUCKET];
    __shared__ int lofs[NBUCKET];
    __shared__ int gbarr[NBUCKET];
    __shared__ int sscan[512];

    int t = threadIdx.x;
    int base = blockIdx.x * EPB;

    // ---- merged cvt: this block's slice of the bf16 feature table ----
    {
        int i = blockIdx.x * 512 + t;                        // one uint4 = 8 bf16
        if (i < NFEATB) {
            const float4* fp = reinterpret_cast<const float4*>(features + i * 8);
            float4 a = fp[0], b = fp[1];
            uint4 o;
            o.x = f2bf(a.x) | (f2bf(a.y) << 16);
            o.y = f2bf(a.z) | (f2bf(a.w) << 16);
            o.z = f2bf(b.x) | (f2bf(b.y) << 16);
            o.w = f2bf(b.z) | (f2bf(b.w) << 16);
            featb[i] = o;
        }
    }

    for (int i = t; i < NBUCKET; i += 512) lh[i] = 0;
    __syncthreads();

    int rr[8]; int bb[8];
    #pragma unroll
    for (int q = 0; q < 8; ++q) {
        int e = base + t + 512 * q;
        if (e < N_EDGES) {
            int d = dst[e];
            bb[q] = d >> 8;
            rr[q] = (src[e] << 11) | (etype[e] << 8) | (d & 255);
            atomicAdd(&lh[bb[q]], 1);
        } else bb[q] = -1;
    }
    __syncthreads();

    int i0 = t * 4;
    int v0 = 0, v1 = 0, v2 = 0, v3 = 0;
    if (i0     < NBUCKET) v0 = lh[i0];
    if (i0 + 1 < NBUCKET) v1 = lh[i0 + 1];
    if (i0 + 2 < NBUCKET) v2 = lh[i0 + 2];
    if (i0 + 3 < NBUCKET) v3 = lh[i0 + 3];
    int tsum = v0 + v1 + v2 + v3;
    sscan[t] = tsum;
    __syncthreads();
    for (int off = 1; off < 512; off <<= 1) {
        int tmp = (t >= off) ? sscan[t - off] : 0;
        __syncthreads();
        sscan[t] += tmp;
        __syncthreads();
    }
    int excl = sscan[t] - tsum;
    if (i0     < NBUCKET) { lscan[i0]     = excl; lofs[i0]     = excl; gbarr[i0]     = v0 ? atomicAdd(&gcursor[i0],     v0) : 0; } excl += v0;
    if (i0 + 1 < NBUCKET) { lscan[i0 + 1] = excl; lofs[i0 + 1] = excl; gbarr[i0 + 1] = v1 ? atomicAdd(&gcursor[i0 + 1], v1) : 0; } excl += v1;
    if (i0 + 2 < NBUCKET) { lscan[i0 + 2] = excl; lofs[i0 + 2] = excl; gbarr[i0 + 2] = v2 ? atomicAdd(&gcursor[i0 + 2], v2) : 0; } excl += v2;
    if (i0 + 3 < NBUCKET) { lscan[i0 + 3] = excl; lofs[i0 + 3] = excl; gbarr[i0 + 3] = v3 ? atomicAdd(&gcursor[i0 + 3], v3) : 0; }
    __syncthreads();

    #pragma unroll
    for (int q = 0; q < 8; ++q) {
        if (bb[q] >= 0) {
            int sidx = atomicAdd(&lofs[bb[q]], 1);
            srec[sidx] = rr[q];
            sbkt[sidx] = (unsigned short)bb[q];
        }
    }
    __syncthreads();

    int cnt = min(EPB, N_EDGES - base);
    for (int s2 = t; s2 < cnt; s2 += 512) {
        int b2 = sbkt[s2];
        int pos = gbarr[b2] + (s2 - lscan[b2]);              // rank within bucket b2
        if (pos < REC_CAP)                 // overflow clamp (never expected, 16 sigma)
            records[b2 * REC_CAP + pos] = srec[s2];
    }
}

// ---- Phase 2: full 2048-bin counting sort per coarse bucket (round-0 exact) ----
// key = (dst&255)*8 + etype; emits slot_off[cb][2049] and sorted records2.
__global__ void __launch_bounds__(256) partition2_kernel(
    const int* __restrict__ gcursor,
    const int* __restrict__ records,
    int* __restrict__ records2,
    int* __restrict__ slot_off)
{
    __shared__ int hist[NSLOT];    // 8 KB; becomes cursor after scan
    __shared__ int sscan[256];
    __shared__ int srec[REC_CAP];  // 20 KB

    int cb = blockIdx.x;
    int beg = cb * REC_CAP;
    int cnt = min(gcursor[cb], REC_CAP);   // gcursor is now a count
    int t = threadIdx.x;

    #pragma unroll
    for (int j = 0; j < 8; ++j) hist[t * 8 + j] = 0;
    __syncthreads();

    for (int i = t; i < cnt; i += 256) {
        int r = records[beg + i];
        atomicAdd(&hist[((r & 255) << 3) | ((r >> 8) & 7)], 1);
    }
    __syncthreads();

    int loc[8]; int tsum = 0;
    #pragma unroll
    for (int j = 0; j < 8; ++j) { loc[j] = hist[t * 8 + j]; tsum += loc[j]; }
    sscan[t] = tsum;
    __syncthreads();
    for (int off = 1; off < 256; off <<= 1) {
        int tmp = (t >= off) ? sscan[t - off] : 0;
        __syncthreads();
        sscan[t] += tmp;
        __syncthreads();
    }
    int excl = sscan[t] - tsum;
    #pragma unroll
    for (int j = 0; j < 8; ++j) {
        slot_off[cb * (NSLOT + 1) + t * 8 + j] = beg + excl;
        hist[t * 8 + j] = excl;    // cursor
        excl += loc[j];
    }
    if (t == 0) slot_off[cb * (NSLOT + 1) + NSLOT] = beg + cnt;
    __syncthreads();

    for (int i = t; i < cnt; i += 256) {
        int r = records[beg + i];
        int pos = atomicAdd(&hist[((r & 255) << 3) | ((r >> 8) & 7)], 1);
        srec[pos] = r;
    }
    __syncthreads();
    for (int i = t; i < cnt; i += 256) records2[beg + i] = srec[i];
}

// ---- Phase 3: persistent fused (round-0-exact body) ----
// Thread t = dl*8 + q: dl = node-in-subbucket (0..31), q = etype (0..7).
// Scheduling change ONLY: 6 blocks/CU (LDS 26112B x 6 = 157KB <= 160KB), FGRID=1536
// all resident at t=0; blocks 0-55 do 3 units, rest do 2 (vs round-0's 4-round ceil).
__global__ void __launch_bounds__(256, 6) fused_kernel(
    const uint4* __restrict__ featb,
    const float* __restrict__ features,
    const int*   __restrict__ slot_off,
    const int*   __restrict__ records2,
    const float* __restrict__ edge_matrix,
    const float* __restrict__ w_ih,
    const float* __restrict__ w_hh,
    const float* __restrict__ b_ih,
    const float* __restrict__ b_hh,
    const float* __restrict__ out_w,
    const float* __restrict__ out_b,
    float*       __restrict__ out)
{
    __shared__ float A[N_ETYPE * A_STRIDE];   // 8.3 KB
    __shared__ float hnT[HID][SBSIZE + 1];    // 2.1 KB
    __shared__ float outS[SBSIZE * 44];       // 5.6 KB
    __shared__ float wihL[3 * HID * 17];      // 3.2 KB (row stride 17)
    __shared__ float whhL[3 * HID * 17];      // 3.2 KB
    __shared__ float outwL[N_CLASSES * 17];   // 2.7 KB
    __shared__ float bihL[3 * HID];
    __shared__ float bhhL[3 * HID];
    __shared__ float outbL[N_CLASSES];

    int t = threadIdx.x;
    int dl = t >> 3, q = t & 7;
    const float4* feat4 = reinterpret_cast<const float4*>(features);

    // stage constants ONCE (padded layouts)
    for (int i = t; i < N_ETYPE * MSG * HID; i += 256)
        A[(i >> 8) * A_STRIDE + (i & 255)] = edge_matrix[i];
    for (int i = t; i < 3 * HID * MSG; i += 256) wihL[(i >> 4) * 17 + (i & 15)] = w_ih[i];
    for (int i = t; i < 3 * HID * HID; i += 256) whhL[(i >> 4) * 17 + (i & 15)] = w_hh[i];
    for (int i = t; i < N_CLASSES * HID; i += 256) outwL[(i >> 4) * 17 + (i & 15)] = out_w[i];
    if (t < 48) bihL[t] = b_ih[t];
    else if (t < 96) bhhL[t - 48] = b_hh[t - 48];
    else if (t < 136) outbL[t - 96] = out_b[t - 96];

    for (int b = blockIdx.x; b < NSB; b += FGRID) {
        int nodeBase = b * SBSIZE;
        if (nodeBase >= N_NODES) continue;
        int cb = b >> 3, sb = b & 7;
        __syncthreads();   // staging / previous iteration's output copy complete

        // ---- edge phase: serial register accumulation over this thread's slot run ----
        int go = cb * (NSLOT + 1) + sb * 256 + t;
        int begin = slot_off[go], end = slot_off[go + 1];

        float acc[16];
        #pragma unroll
        for (int k = 0; k < 16; ++k) acc[k] = 0.0f;
        for (int i = begin; i < end; ++i) {
            int rec = records2[i];
            int sn = rec >> 11;
            uint4 ua = featb[2 * sn], ub = featb[2 * sn + 1];
            acc[0]  += bflo(ua.x); acc[1]  += bfhi(ua.x);
            acc[2]  += bflo(ua.y); acc[3]  += bfhi(ua.y);
            acc[4]  += bflo(ua.z); acc[5]  += bfhi(ua.z);
            acc[6]  += bflo(ua.w); acc[7]  += bfhi(ua.w);
            acc[8]  += bflo(ub.x); acc[9]  += bfhi(ub.x);
            acc[10] += bflo(ub.y); acc[11] += bfhi(ub.y);
            acc[12] += bflo(ub.z); acc[13] += bfhi(ub.z);
            acc[14] += bflo(ub.w); acc[15] += bfhi(ub.w);
        }

        // ---- matvec partial: p[mm] = A[q][mm][:] . acc  (broadcast LDS reads) ----
        float p[16];
        {
            const float* Aq = &A[q * A_STRIDE];
            #pragma unroll
            for (int mm = 0; mm < 16; ++mm) {
                const float4* Ar = reinterpret_cast<const float4*>(Aq + mm * 16);
                float4 x0 = Ar[0], x1 = Ar[1], x2 = Ar[2], x3 = Ar[3];
                p[mm] = x0.x*acc[0]  + x0.y*acc[1]  + x0.z*acc[2]  + x0.w*acc[3]
                      + x1.x*acc[4]  + x1.y*acc[5]  + x1.z*acc[6]  + x1.w*acc[7]
                      + x2.x*acc[8]  + x2.y*acc[9]  + x2.z*acc[10] + x2.w*acc[11]
                      + x3.x*acc[12] + x3.y*acc[13] + x3.z*acc[14] + x3.w*acc[15];
            }
        }
        // ---- reduce the 8 etype partials per node via shuffles ----
        #pragma unroll
        for (int mm = 0; mm < 16; ++mm) {
            p[mm] += __shfl_xor(p[mm], 1, 64);
            p[mm] += __shfl_xor(p[mm], 2, 64);
            p[mm] += __shfl_xor(p[mm], 4, 64);
        }

        // ---- GRU: thread (dl,q) computes gate rows j = 2q, 2q+1 ----
        int n = nodeBase + dl;
        float hva[16];
        {
            const float4* hp = feat4 + (size_t)n * 4;
            float4 h0 = hp[0], h1 = hp[1], h2 = hp[2], h3 = hp[3];
            hva[0]=h0.x; hva[1]=h0.y; hva[2]=h0.z; hva[3]=h0.w;
            hva[4]=h1.x; hva[5]=h1.y; hva[6]=h1.z; hva[7]=h1.w;
            hva[8]=h2.x; hva[9]=h2.y; hva[10]=h2.z; hva[11]=h2.w;
            hva[12]=h3.x; hva[13]=h3.y; hva[14]=h3.z; hva[15]=h3.w;
        }
        #pragma unroll
        for (int jj = 0; jj < 2; ++jj) {
            int j = 2 * q + jj;
            float ir  = bihL[j];
            float iz  = bihL[j + HID];
            float inn = bihL[j + 2 * HID];
            float hr  = bhhL[j];
            float hz  = bhhL[j + HID];
            float hnn = bhhL[j + 2 * HID];
            const float* wir = &wihL[j * 17];
            const float* wiz = &wihL[(j + HID) * 17];
            const float* win = &wihL[(j + 2 * HID) * 17];
            const float* whr = &whhL[j * 17];
            const float* whz = &whhL[(j + HID) * 17];
            const float* whn = &whhL[(j + 2 * HID) * 17];
            #pragma unroll
            for (int k = 0; k < HID; ++k) {
                ir  += wir[k] * p[k];
                iz  += wiz[k] * p[k];
                inn += win[k] * p[k];
                hr  += whr[k] * hva[k];
                hz  += whz[k] * hva[k];
                hnn += whn[k] * hva[k];
            }
            float rg = sigmoidf_(ir + hr);
            float zg = sigmoidf_(iz + hz);
            float cg = tanhf_(inn + rg * hnn);
            hnT[j][dl] = (1.0f - zg) * cg + zg * hva[j];
        }
        __syncthreads();

        // ---- head: thread (dl,q) computes classes c = 5q..5q+4 ----
        {
            float hh[HID];
            #pragma unroll
            for (int k = 0; k < HID; ++k) hh[k] = hnT[k][dl];
            #pragma unroll
            for (int cc = 0; cc < 5; ++cc) {
                int c = 5 * q + cc;
                float a2 = outbL[c];
                const float* wr = &outwL[c * 17];
                #pragma unroll
                for (int k = 0; k < HID; ++k) a2 += wr[k] * hh[k];
                outS[dl * 44 + c] = a2;
            }
        }
        __syncthreads();

        // ---- coalesced float4 output copy ----
        {
            float4* ob4 = reinterpret_cast<float4*>(out + (size_t)nodeBase * N_CLASSES);
            #pragma unroll
            for (int rep = 0; rep < 2; ++rep) {
                int i = t + rep * 256;
                if (i < SBSIZE * N_CLASSES / 4) {
                    int node = i / 10, qq = i - node * 10;
                    ob4[i] = *reinterpret_cast<const float4*>(&outS[node * 44 + qq * 4]);
                }
            }
        }
    }
}

extern "C" void kernel_launch(void* const* d_in, const int* in_sizes, int n_in,
                              void* d_out, int out_size, void* d_ws, size_t ws_size,
                              hipStream_t stream) {
    const float* features    = (const float*)d_in[0];
    const int*   src         = (const int*)  d_in[1];
    const int*   dst         = (const int*)  d_in[2];
    const int*   etype       = (const int*)  d_in[3];
    const float* edge_matrix = (const float*)d_in[4];
    const float* w_ih        = (const float*)d_in[5];
    const float* w_hh        = (const float*)d_in[6];
    const float* b_ih        = (const float*)d_in[7];
    const float* b_hh        = (const float*)d_in[8];
    const float* out_w       = (const float*)d_in[9];
    const float* out_b       = (const float*)d_in[10];
    float* out = (float*)d_out;

    // ws (ints): gcursor[NB] | slot_off[NB*2049] | records[NB*CAP] | records2[NB*CAP] | featb (16B aligned)
    int* gcursor  = (int*)d_ws;
    int* slot_off = gcursor + NBUCKET;
    int* records  = slot_off + NBUCKET * (NSLOT + 1);
    int* records2 = records + NBUCKET * REC_CAP;
    size_t featb_off = ((size_t)((char*)(records2 + NBUCKET * REC_CAP) - (char*)d_ws) + 15) & ~15ull;
    uint4* featb = (uint4*)((char*)d_ws + featb_off);

    hipMemsetAsync(gcursor, 0, NBUCKET * sizeof(int), stream);   // gcursor = per-bucket count
    partition_kernel<<<NEBLK, 512, 0, stream>>>(features, featb, src, dst, etype, gcursor, records);
    partition2_kernel<<<NBUCKET, 256, 0, stream>>>(gcursor, records, records2, slot_off);
    fused_kernel<<<FGRID, 256, 0, stream>>>(
        featb, features, slot_off, records2, edge_matrix,
        w_ih, w_hh, b_ih, b_hh, out_w, out_b, out);
}